// Round 1
// baseline (130.317 us; speedup 1.0000x reference)
//
#include <hip/hip_runtime.h>

// TopologyNetwork: B=1024, N=5000, K=16, 9 levels.
// R14 = R13 + LDS bank-conflict elimination via edge-slot matching:
//  - Activations stored TWICE per level: copy A at slot s, copy B at slot
//    5008 + sigma(s), sigma(s) = (s&15)*313 + (s>>4) (injective, bank-pair
//    = pseudo-independent hash). 2 x 10016 slots x 8B = 160,256 B LDS.
//  - k_pack2 (one thread per node): greedy two-choice matching assigns each
//    edge to gather-step k such that its bank-pair == (n+k) mod 16. Lanes
//    hold consecutive nodes, so a matched step hits every bank-pair exactly
//    4x across the wave = conflict-free (the b64 floor). ~90% matched.
//  - v_pk_fma_f16 op_sel:[1,0,0] broadcasts the f16 weight from the packed
//    word's high half -> drops the per-edge v_perm.

#define TB 1024
#define TN 5000
#define TK 16
#define TLV 9
#define CPG 4                   // f16 cols per group (8 B per node-row)
#define NG  (TB / CPG)          // 256 col-groups = grid
#define LT  1024                // threads per block (16 waves)
#define PEL (TN * TK)           // u32 per level in packed-edge array

#define SLOTS_A 5008            // copy A occupies slots [0,5000), pad to x16
#define SLOTS   10016           // per logical buffer: A + B copies

typedef unsigned int u32;
typedef unsigned short u16;
typedef _Float16 h2 __attribute__((ext_vector_type(2)));

__device__ __forceinline__ h2 u2h(u32 v) { return __builtin_bit_cast(h2, v); }
__device__ __forceinline__ u32 h2u(h2 h) { return __builtin_bit_cast(u32, h); }
__device__ __forceinline__ u32 packf(float a, float b) {
    h2 h; h.x = (_Float16)a; h.y = (_Float16)b;
    return h2u(h);
}
// injective remap for copy B; bank-pair sigma(s)&15 = (9*(s&15)+(s>>4))&15
__device__ __forceinline__ u32 sigma(u32 n) { return (n & 15u) * 313u + (n >> 4); }

// ---- pack + per-node two-choice slot matching ----
// One thread per (level,node). Edge j of node n gets gather-step k such that
// its LDS slot's bank-pair == (n+k) mod 16 when possible (choice of copy A/B).
__global__ __launch_bounds__(256) void k_pack2(
    const int* __restrict__ idx, const float* __restrict__ w,
    u32* __restrict__ pe)
{
    __shared__ u32 asg[256][17];          // 17: kill LDS bank conflicts
    const int t = threadIdx.x;
    const int j = blockIdx.x * 256 + t;   // (level,node) id
    const int NT = TLV * TN;              // 45000

    if (j < NT) {
        const u32 n  = (u32)(j % TN);
        const int eb = j * TK;
        const int4*   ip = reinterpret_cast<const int4*>(idx + eb);
        const float4* wp = reinterpret_cast<const float4*>(w + eb);
        const int4   i0 = ip[0], i1 = ip[1], i2 = ip[2], i3 = ip[3];
        const float4 w0 = wp[0], w1 = wp[1], w2 = wp[2], w3 = wp[3];
        const int   si[TK] = {i0.x,i0.y,i0.z,i0.w, i1.x,i1.y,i1.z,i1.w,
                              i2.x,i2.y,i2.z,i2.w, i3.x,i3.y,i3.z,i3.w};
        const float wv[TK] = {w0.x,w0.y,w0.z,w0.w, w1.x,w1.y,w1.z,w1.w,
                              w2.x,w2.y,w2.z,w2.w, w3.x,w3.y,w3.z,w3.w};

        u32 used = 0, pendmask = 0;
        u32 valA[TK];
        #pragma unroll
        for (int k = 0; k < TK; ++k) {
            const u32 s = (u32)si[k];
            h2 hw; hw.x = (_Float16)wv[k]; hw.y = (_Float16)0.0f;
            const u32 wb = h2u(hw) << 16;       // f16 weight in high 16
            const u32 offA = s;                 // copy-A slot
            const u32 offB = SLOTS_A + sigma(s);// copy-B slot
            valA[k] = offA | wb;
            const u32 kA = (offA - n) & 15u;    // step with matching bank-pair
            const u32 kB = (offB - n) & 15u;
            if (!((used >> kA) & 1u))      { used |= 1u << kA; asg[t][kA] = offA | wb; }
            else if (!((used >> kB) & 1u)) { used |= 1u << kB; asg[t][kB] = offB | wb; }
            else pendmask |= 1u << k;
        }
        #pragma unroll
        for (int k = 0; k < TK; ++k) {          // fallback: any free slot
            if ((pendmask >> k) & 1u) {
                const u32 slot = (u32)__builtin_ctz(~used);
                used |= 1u << slot;
                asg[t][slot] = valA[k];
            }
        }
    }
    __syncthreads();

    // coalesced write-out of the block's 256 nodes x 16 slots
    const int jb    = blockIdx.x * 256;
    const int nodeN = min(256, NT - jb);
    const int elems = nodeN * TK;
    for (int p = t; p < elems; p += 256)
        pe[(size_t)jb * TK + p] = asg[p >> 4][p & 15];
}

// ---- fused: transpose-in + 9 levels in LDS + transpose-out ----
__global__ __launch_bounds__(LT) void k_fused(
    const float* __restrict__ x,      // [B,N]
    float* __restrict__ out,          // [B,N]
    const u32* __restrict__ pe,       // [LV][TN][TK] (slot | f16w<<16)
    const float* __restrict__ biases) // [LV][TN]
{
    __shared__ uint2 buf[2][SLOTS];   // 2 x 80,128 B ping-pong, A+B copies
    const int g = blockIdx.x;
    const int t = threadIdx.x;

    // stage x cols g*4..g*4+3 as f16 rows, into both copies
    {
        const float* xp0 = x + (size_t)(g * CPG + 0) * TN;
        const float* xp1 = x + (size_t)(g * CPG + 1) * TN;
        const float* xp2 = x + (size_t)(g * CPG + 2) * TN;
        const float* xp3 = x + (size_t)(g * CPG + 3) * TN;
        for (int n = t; n < TN; n += LT) {
            uint2 v;
            v.x = packf(xp0[n], xp1[n]);
            v.y = packf(xp2[n], xp3[n]);
            buf[0][n] = v;
            buf[0][SLOTS_A + sigma((u32)n)] = v;
        }
    }
    __syncthreads();

    int cur = 0;
    for (int l = 0; l < TLV; ++l) {
        const u32*   ep_l = pe + (size_t)l * PEL;
        const float* b_l  = biases + (size_t)l * TN;
        const char*  base = reinterpret_cast<const char*>(buf[cur]);
        uint2* wb = buf[cur ^ 1];
        for (int n = t; n < TN; n += LT) {
            // 16 edges of node n: 64 B contiguous -> 4x dwordx4
            const uint4* ep = reinterpret_cast<const uint4*>(ep_l + (size_t)n * TK);
            const uint4 e0 = ep[0];
            const uint4 e1 = ep[1];
            const uint4 e2 = ep[2];
            const uint4 e3 = ep[3];
            const u32 es[TK] = {e0.x, e0.y, e0.z, e0.w,
                                e1.x, e1.y, e1.z, e1.w,
                                e2.x, e2.y, e2.z, e2.w,
                                e3.x, e3.y, e3.z, e3.w};

            const float bvf = b_l[n];
            u32 a01 = packf(bvf, bvf);
            u32 a23 = a01;

            #pragma unroll
            for (int k = 0; k < TK; ++k) {
                const u32 e   = es[k];
                const u32 off = (e & 0xffffu) << 3;        // slot*8 bytes
                const uint2 av = *reinterpret_cast<const uint2*>(base + off);
                // acc += w(hi16 of e) * av  (both halves), no v_perm needed
                asm("v_pk_fma_f16 %0, %1, %2, %0 op_sel:[1,0,0] op_sel_hi:[1,1,1]"
                    : "+v"(a01) : "v"(e), "v"(av.x));
                asm("v_pk_fma_f16 %0, %1, %2, %0 op_sel:[1,0,0] op_sel_hi:[1,1,1]"
                    : "+v"(a23) : "v"(e), "v"(av.y));
            }

            // LeakyReLU(0.1) = max(x, 0.1*x)
            h2 A = u2h(a01), Bv = u2h(a23);
            h2 tenth; tenth.x = (_Float16)0.1f; tenth.y = (_Float16)0.1f;
            A  = __builtin_elementwise_max(A,  A  * tenth);
            Bv = __builtin_elementwise_max(Bv, Bv * tenth);

            uint2 r; r.x = h2u(A); r.y = h2u(Bv);
            wb[n] = r;
            wb[SLOTS_A + sigma((u32)n)] = r;   // copy B (conflict-free write)
        }
        __syncthreads();
        cur ^= 1;
    }

    // write out cols g*4..g*4+3 (from copy A)
    {
        float* op0 = out + (size_t)(g * CPG + 0) * TN;
        float* op1 = out + (size_t)(g * CPG + 1) * TN;
        float* op2 = out + (size_t)(g * CPG + 2) * TN;
        float* op3 = out + (size_t)(g * CPG + 3) * TN;
        for (int n = t; n < TN; n += LT) {
            const uint2 v = buf[cur][n];
            h2 h;
            h = u2h(v.x); op0[n] = (float)h.x; op1[n] = (float)h.y;
            h = u2h(v.y); op2[n] = (float)h.x; op3[n] = (float)h.y;
        }
    }
}

extern "C" void kernel_launch(void* const* d_in, const int* in_sizes, int n_in,
                              void* d_out, int out_size, void* d_ws, size_t ws_size,
                              hipStream_t stream)
{
    const float* x       = (const float*)d_in[0];   // [B,N]
    const int*   src_idx = (const int*)  d_in[1];   // [LV,N,K]
    const float* weights = (const float*)d_in[2];   // [LV,N,K]
    const float* biases  = (const float*)d_in[3];   // [LV,N]
    float* out = (float*)d_out;                     // [B,N]

    u32* pe = (u32*)d_ws;                           // [LV][TN][TK] = 2.88 MB

    // pack + per-node two-choice slot matching
    {
        const int nn = TLV * TN;                    // 45000 nodes
        hipLaunchKernelGGL(k_pack2, dim3((nn + 255) / 256), dim3(256), 0, stream,
                           src_idx, weights, pe);
    }
    // fused 9-level evaluation
    hipLaunchKernelGGL(k_fused, dim3(NG), dim3(LT), 0, stream,
                       x, out, pe, biases);
}